// Round 7
// baseline (7664.008 us; speedup 1.0000x reference)
//
#include <hip/hip_runtime.h>

typedef unsigned short u16;
typedef __attribute__((ext_vector_type(8))) short short8;
typedef __attribute__((ext_vector_type(4))) float floatx4;

__device__ __forceinline__ float bf2f(u16 u) {
  unsigned int v = ((unsigned int)u) << 16;
  return __builtin_bit_cast(float, v);
}
__device__ __forceinline__ u16 f2bf(float f) {
  unsigned int u = __builtin_bit_cast(unsigned int, f);
  u += 0x7FFFu + ((u >> 16) & 1u);
  return (u16)(u >> 16);
}
// external-input load with runtime dtype (branch, not ternary: avoid speculating wrong-interp loads)
__device__ __forceinline__ float ldx(const void* p, size_t i, int sel) {
  if (sel) return ((const float*)p)[i];
  return bf2f(((const u16*)p)[i]);
}

// Decide external dtype: 1 = fp32 (expected), 0 = bf16. Reads 2M elems, safe under both.
__global__ __launch_bounds__(256) void sniff_dtype(const void* x, int* selp) {
  __shared__ int sB[256], sF[256];
  int t = threadIdx.x;
  int bB = 0, bF = 0;
  for (long i = t; i < 2 * 1024 * 1024; i += 256) {
    float fb = bf2f(((const u16*)x)[i]);
    if (!(fabsf(fb) <= 100.f)) bB++;
    float ff = ((const float*)x)[i];
    if (!(fabsf(ff) <= 100.f)) bF++;
  }
  sB[t] = bB; sF[t] = bF;
  __syncthreads();
  if (t == 0) {
    int a = 0, b = 0;
    for (int i = 0; i < 256; i++) { a += sB[i]; b += sF[i]; }
    *selp = (b < a) ? 1 : 0;
  }
}

// ---------------- layernorm (Bessel std, eps added to std) -> bf16 ----------------
// XMODE 0: input external (sel dtype); XMODE 1: input fp32 workspace
template <int XMODE>
__global__ __launch_bounds__(256) void ln_any(const void* __restrict__ xin,
                                              const void* __restrict__ wgt,
                                              const void* __restrict__ bia,
                                              const int* __restrict__ selp,
                                              u16* __restrict__ out) {
  int sel = *selp;
  int row = blockIdx.x, t = threadIdx.x;
  float v[4];
#pragma unroll
  for (int j = 0; j < 4; j++) {
    size_t i = (size_t)row * 1024 + t * 4 + j;
    v[j] = (XMODE == 1) ? ((const float*)xin)[i] : ldx(xin, i, sel);
  }
  float s1 = v[0] + v[1] + v[2] + v[3];
  float s2 = v[0] * v[0] + v[1] * v[1] + v[2] * v[2] + v[3] * v[3];
#pragma unroll
  for (int off = 32; off; off >>= 1) {
    s1 += __shfl_down(s1, off);
    s2 += __shfl_down(s2, off);
  }
  __shared__ float red[8];
  int lane = t & 63, w = t >> 6;
  if (lane == 0) { red[w] = s1; red[4 + w] = s2; }
  __syncthreads();
  s1 = red[0] + red[1] + red[2] + red[3];
  s2 = red[4] + red[5] + red[6] + red[7];
  float mean = s1 * (1.f / 1024.f);
  float var = (s2 - 1024.f * mean * mean) * (1.f / 1023.f);
  var = var < 0.f ? 0.f : var;
  float inv = 1.f / (sqrtf(var) + 1e-5f);
#pragma unroll
  for (int j = 0; j < 4; j++) {
    int c = t * 4 + j;
    out[(size_t)row * 1024 + c] = f2bf(ldx(wgt, c, sel) * ((v[j] - mean) * inv) + ldx(bia, c, sel));
  }
}

// ------- MFMA GEMM: C = A(bf16,[M][K]) @ B(ext fp32/bf16,[K][N] ldb,+brow0,+bcol0) -------
// EPI 0: bf16 out = v + bias[bcol0+gn]            (qkv)
// EPI 1: f32 out = v + bias[gn] + res_ext[o]      (c_proj + residual x)
// EPI 2: bf16 out = gelu(v + bias[bcol0+gn])      (fc)
// EPI 3: f32 out += v                              (proj chunk)
// EPI 4: f32 out += v + bias[gn]                   (last proj chunk)
template <int EPI>
__global__ __launch_bounds__(256) void gemm_mfma(const u16* __restrict__ A,
                                                 const void* __restrict__ B,
                                                 const void* __restrict__ bias,
                                                 const void* __restrict__ res,
                                                 void* __restrict__ outp,
                                                 int K, int ldb, int ldc,
                                                 int brow0, int bcol0,
                                                 const int* __restrict__ selp) {
  int sel = *selp;
  __shared__ __align__(16) u16 As[128 * 64];   // [m][k]
  __shared__ __align__(16) u16 Bs[128 * 64];   // [n][k ^ sw(n)]
  int tid = threadIdx.x;
  int lane = tid & 63, w = tid >> 6;
  int quad = lane >> 4, c16 = lane & 15;
  int wm = w >> 1, wn = w & 1;
  int bn = blockIdx.x, bm = blockIdx.y;
  const u16* Ab = A + (size_t)bm * 128 * K;

  floatx4 zf = {0.f, 0.f, 0.f, 0.f};
  floatx4 acc[4][4];
#pragma unroll
  for (int i = 0; i < 4; i++)
#pragma unroll
    for (int j = 0; j < 4; j++) acc[i][j] = zf;

  int krow = tid >> 4;          // 0..15
  int ncol = (tid & 15) * 8;    // 0..120
  int swb = ((ncol >> 3) & 7) << 3;

  int kIters = K >> 6;
  for (int kt = 0; kt < kIters; ++kt) {
    __syncthreads();
    short8 av[4];
#pragma unroll
    for (int t2 = 0; t2 < 4; ++t2) {
      int idx = (w * 4 + t2) * 512 + lane * 8;
      int r = idx >> 6, c = idx & 63;
      av[t2] = *(const short8*)(Ab + (size_t)r * K + kt * 64 + c);
    }
    float btmp[4][8];
    if (sel) {
#pragma unroll
      for (int p = 0; p < 4; ++p) {
        int k = p * 16 + krow;
        const float* bp = (const float*)B + (size_t)(brow0 + kt * 64 + k) * ldb + bcol0 + bn * 128 + ncol;
        float4 f0 = *(const float4*)bp;
        float4 f1 = *(const float4*)(bp + 4);
        btmp[p][0] = f0.x; btmp[p][1] = f0.y; btmp[p][2] = f0.z; btmp[p][3] = f0.w;
        btmp[p][4] = f1.x; btmp[p][5] = f1.y; btmp[p][6] = f1.z; btmp[p][7] = f1.w;
      }
    } else {
#pragma unroll
      for (int p = 0; p < 4; ++p) {
        int k = p * 16 + krow;
        const u16* bp = (const u16*)B + (size_t)(brow0 + kt * 64 + k) * ldb + bcol0 + bn * 128 + ncol;
#pragma unroll
        for (int j = 0; j < 8; ++j) btmp[p][j] = bf2f(bp[j]);
      }
    }
#pragma unroll
    for (int t2 = 0; t2 < 4; ++t2)
      *(short8*)&As[(w * 4 + t2) * 512 + lane * 8] = av[t2];
#pragma unroll
    for (int p = 0; p < 4; ++p) {
      int k = p * 16 + krow;
#pragma unroll
      for (int j = 0; j < 8; ++j)
        Bs[(ncol + j) * 64 + (k ^ swb)] = f2bf(btmp[p][j]);
    }
    __syncthreads();
#pragma unroll
    for (int ks = 0; ks < 2; ++ks) {
      short8 af[4], bfr[4];
#pragma unroll
      for (int mt = 0; mt < 4; mt++)
        af[mt] = *(const short8*)&As[(wm * 64 + mt * 16 + c16) * 64 + ks * 32 + quad * 8];
#pragma unroll
      for (int nt = 0; nt < 4; nt++) {
        int n = wn * 64 + nt * 16 + c16;
        int sw = ((n >> 3) & 7) << 3;
        bfr[nt] = *(const short8*)&Bs[n * 64 + ((ks * 32 + quad * 8) ^ sw)];
      }
#pragma unroll
      for (int mt = 0; mt < 4; mt++)
#pragma unroll
        for (int nt = 0; nt < 4; nt++)
          acc[mt][nt] = __builtin_amdgcn_mfma_f32_16x16x32_bf16(af[mt], bfr[nt], acc[mt][nt], 0, 0, 0);
    }
  }
  // epilogue: C layout col=lane&15, row=quad*4+reg
  int gm0 = bm * 128 + wm * 64;
  int gn0 = bn * 128 + wn * 64;
#pragma unroll
  for (int nt = 0; nt < 4; nt++) {
    int gn = gn0 + nt * 16 + c16;
    float bia = 0.f;
    if constexpr (EPI == 0 || EPI == 2) bia = ldx(bias, bcol0 + gn, sel);
    else if constexpr (EPI == 1 || EPI == 4) bia = ldx(bias, gn, sel);
#pragma unroll
    for (int mt = 0; mt < 4; mt++) {
#pragma unroll
      for (int r = 0; r < 4; r++) {
        int gm = gm0 + mt * 16 + quad * 4 + r;
        size_t o = (size_t)gm * ldc + gn;
        float v = acc[mt][nt][r] + bia;
        if constexpr (EPI == 0) {
          ((u16*)outp)[o] = f2bf(v);
        } else if constexpr (EPI == 1) {
          ((float*)outp)[o] = v + ldx(res, o, sel);
        } else if constexpr (EPI == 2) {
          float g = 0.5f * v * (1.f + tanhf(0.7978845608f * (v + 0.044715f * v * v * v)));
          ((u16*)outp)[o] = f2bf(g);
        } else if constexpr (EPI == 3) {
          ((float*)outp)[o] += v - bia;  // bia==0 here; keep form identical
        } else {
          ((float*)outp)[o] += v;
        }
      }
    }
  }
}

// ------- causal attention, scalar wave-reduce: one wave per (q row, head) -------
// qkvb: [2048][3072] bf16 (one batch); writes aout rows [q][h*64+d]
__global__ __launch_bounds__(64) void attn_row(const u16* __restrict__ qkvb,
                                               u16* __restrict__ aout) {
  int q = blockIdx.x;       // 0..2047
  int h = blockIdx.y;       // 0..15
  int d = threadIdx.x;      // 0..63
  float qd = bf2f(qkvb[(size_t)q * 3072 + h * 64 + d]);
  float m = -1e30f, l = 0.f, o = 0.f;
  for (int j = 0; j <= q; j++) {
    const u16* kp = qkvb + (size_t)j * 3072 + 1024 + h * 64;
    float s = qd * bf2f(kp[d]);
#pragma unroll
    for (int off = 1; off < 64; off <<= 1) s += __shfl_xor(s, off);
    s *= 0.125f;
    float mn = fmaxf(m, s);
    float al = __expf(m - mn);
    float p = __expf(s - mn);
    l = l * al + p;
    o = o * al + p * bf2f(kp[1024 + d]);
    m = mn;
  }
  aout[(size_t)q * 1024 + h * 64 + d] = f2bf(o / l);
}

extern "C" void kernel_launch(void* const* d_in, const int* in_sizes, int n_in,
                              void* d_out, int out_size, void* d_ws, size_t ws_size,
                              hipStream_t stream) {
  const void* x        = d_in[0];
  const void* ln1_w    = d_in[1];
  const void* ln1_b    = d_in[2];
  const void* c_attn_w = d_in[3];
  const void* c_attn_b = d_in[4];
  const void* c_proj_w = d_in[5];
  const void* c_proj_b = d_in[6];
  const void* ln2_w    = d_in[7];
  const void* ln2_b    = d_in[8];
  const void* fc_w     = d_in[9];
  const void* fc_b     = d_in[10];
  const void* proj_w   = d_in[11];
  const void* proj_b   = d_in[12];

  char* ws = (char*)d_ws;
  // peak ws: 28 MiB + 4 B
  u16*   ln1b     = (u16*)(ws + 0);          // [4096][1024] bf16, dead after qkv gemms
  u16*   qkvb     = (u16*)(ws + 8388608);    // [2048][3072] bf16 per batch, [8,20) MiB
  u16*   attn_out = (u16*)(ws + 20971520);   // [4096][1024] bf16, [20,28) MiB
  u16*   ln2b     = (u16*)(ws + 0);          // [4096][1024] bf16 (reuses ln1b)
  u16*   h_c      = (u16*)(ws + 8388608);    // [4096][1024] bf16 per chunk (reuses qkvb)
  int*   selp     = (int*)(ws + 29360128);   // at 28 MiB
  float* x1       = (float*)d_out;           // [4096][1024] fp32; final output overwrites in place

  sniff_dtype<<<1, 256, 0, stream>>>(x, selp);

  // LN1 -> bf16
  ln_any<0><<<4096, 256, 0, stream>>>(x, ln1_w, ln1_b, selp, ln1b);

  // per batch: qkv = ln1b_batch @ c_attn_w + b  (bf16), then scalar flash attention
  for (int b = 0; b < 2; b++) {
    gemm_mfma<0><<<dim3(24, 16), 256, 0, stream>>>(ln1b + (size_t)b * 2048 * 1024,
                                                   c_attn_w, c_attn_b, nullptr, qkvb,
                                                   1024, 3072, 3072, 0, 0, selp);
    attn_row<<<dim3(2048, 16), 64, 0, stream>>>(qkvb, attn_out + (size_t)b * 2048 * 1024);
  }

  // x1 = attn_out @ c_proj_w + c_proj_b + x  (fp32, into d_out)
  gemm_mfma<1><<<dim3(8, 32), 256, 0, stream>>>(attn_out, c_proj_w, c_proj_b, x, x1,
                                                1024, 1024, 1024, 0, 0, selp);

  // LN2 (reads fp32 x1) -> bf16
  ln_any<1><<<4096, 256, 0, stream>>>(x1, ln2_w, ln2_b, selp, ln2b);

  // MLP in 4 chunks of 1024: h_c = gelu(ln2b @ fc_w[:,c]); x1 += h_c @ proj_w[c,:] (+proj_b last)
  for (int c = 0; c < 4; c++) {
    gemm_mfma<2><<<dim3(8, 32), 256, 0, stream>>>(ln2b, fc_w, fc_b, nullptr, h_c,
                                                  1024, 4096, 1024, 0, c * 1024, selp);
    if (c < 3)
      gemm_mfma<3><<<dim3(8, 32), 256, 0, stream>>>(h_c, proj_w, nullptr, nullptr, x1,
                                                    1024, 1024, 1024, c * 1024, 0, selp);
    else
      gemm_mfma<4><<<dim3(8, 32), 256, 0, stream>>>(h_c, proj_w, proj_b, nullptr, x1,
                                                    1024, 1024, 1024, c * 1024, 0, selp);
  }
}

// Round 8
// 2126.492 us; speedup vs baseline: 3.6041x; 3.6041x over previous
//
#include <hip/hip_runtime.h>

typedef unsigned short u16;
typedef __attribute__((ext_vector_type(8))) short short8;
typedef __attribute__((ext_vector_type(4))) float floatx4;

__device__ __forceinline__ float bf2f(u16 u) {
  unsigned int v = ((unsigned int)u) << 16;
  return __builtin_bit_cast(float, v);
}
__device__ __forceinline__ u16 f2bf(float f) {
  unsigned int u = __builtin_bit_cast(unsigned int, f);
  u += 0x7FFFu + ((u >> 16) & 1u);
  return (u16)(u >> 16);
}
// external-input load with runtime dtype (branch, not ternary: avoid speculating wrong-interp loads)
__device__ __forceinline__ float ldx(const void* p, size_t i, int sel) {
  if (sel) return ((const float*)p)[i];
  return bf2f(((const u16*)p)[i]);
}

// Decide external dtype: 1 = fp32 (expected), 0 = bf16. Reads 2M elems, safe under both.
__global__ __launch_bounds__(256) void sniff_dtype(const void* x, int* selp) {
  __shared__ int sB[256], sF[256];
  int t = threadIdx.x;
  int bB = 0, bF = 0;
  for (long i = t; i < 2 * 1024 * 1024; i += 256) {
    float fb = bf2f(((const u16*)x)[i]);
    if (!(fabsf(fb) <= 100.f)) bB++;
    float ff = ((const float*)x)[i];
    if (!(fabsf(ff) <= 100.f)) bF++;
  }
  sB[t] = bB; sF[t] = bF;
  __syncthreads();
  if (t == 0) {
    int a = 0, b = 0;
    for (int i = 0; i < 256; i++) { a += sB[i]; b += sF[i]; }
    *selp = (b < a) ? 1 : 0;
  }
}

// ---------------- layernorm (Bessel std, eps added to std) -> bf16 ----------------
template <int XMODE>
__global__ __launch_bounds__(256) void ln_any(const void* __restrict__ xin,
                                              const void* __restrict__ wgt,
                                              const void* __restrict__ bia,
                                              const int* __restrict__ selp,
                                              u16* __restrict__ out) {
  int sel = *selp;
  int row = blockIdx.x, t = threadIdx.x;
  float v[4];
#pragma unroll
  for (int j = 0; j < 4; j++) {
    size_t i = (size_t)row * 1024 + t * 4 + j;
    v[j] = (XMODE == 1) ? ((const float*)xin)[i] : ldx(xin, i, sel);
  }
  float s1 = v[0] + v[1] + v[2] + v[3];
  float s2 = v[0] * v[0] + v[1] * v[1] + v[2] * v[2] + v[3] * v[3];
#pragma unroll
  for (int off = 32; off; off >>= 1) {
    s1 += __shfl_down(s1, off);
    s2 += __shfl_down(s2, off);
  }
  __shared__ float red[8];
  int lane = t & 63, w = t >> 6;
  if (lane == 0) { red[w] = s1; red[4 + w] = s2; }
  __syncthreads();
  s1 = red[0] + red[1] + red[2] + red[3];
  s2 = red[4] + red[5] + red[6] + red[7];
  float mean = s1 * (1.f / 1024.f);
  float var = (s2 - 1024.f * mean * mean) * (1.f / 1023.f);
  var = var < 0.f ? 0.f : var;
  float inv = 1.f / (sqrtf(var) + 1e-5f);
#pragma unroll
  for (int j = 0; j < 4; j++) {
    int c = t * 4 + j;
    out[(size_t)row * 1024 + c] = f2bf(ldx(wgt, c, sel) * ((v[j] - mean) * inv) + ldx(bia, c, sel));
  }
}

// ------- MFMA GEMM: C = A(bf16,[M][K]) @ B(ext fp32/bf16,[K][N] ldb,+brow0,+bcol0) -------
// EPI 0: bf16 out = v + bias[bcol0+gn]            (qkv)
// EPI 1: f32 out = v + bias[gn] + res_ext[o]      (c_proj + residual x)
// EPI 2: bf16 out = gelu(v + bias[bcol0+gn])      (fc)
// EPI 3: f32 out += v                              (proj chunk)
// EPI 4: f32 out += v + bias[gn]                   (last proj chunk)
template <int EPI>
__global__ __launch_bounds__(256) void gemm_mfma(const u16* __restrict__ A,
                                                 const void* __restrict__ B,
                                                 const void* __restrict__ bias,
                                                 const void* __restrict__ res,
                                                 void* __restrict__ outp,
                                                 int K, int ldb, int ldc,
                                                 int brow0, int bcol0,
                                                 const int* __restrict__ selp) {
  int sel = *selp;
  __shared__ __align__(16) u16 As[128 * 64];   // [m][k]
  __shared__ __align__(16) u16 Bs[128 * 64];   // [n][k ^ sw(n)]
  int tid = threadIdx.x;
  int lane = tid & 63, w = tid >> 6;
  int quad = lane >> 4, c16 = lane & 15;
  int wm = w >> 1, wn = w & 1;
  int bn = blockIdx.x, bm = blockIdx.y;
  const u16* Ab = A + (size_t)bm * 128 * K;

  floatx4 zf = {0.f, 0.f, 0.f, 0.f};
  floatx4 acc[4][4];
#pragma unroll
  for (int i = 0; i < 4; i++)
#pragma unroll
    for (int j = 0; j < 4; j++) acc[i][j] = zf;

  int krow = tid >> 4;          // 0..15
  int ncol = (tid & 15) * 8;    // 0..120
  int swb = ((ncol >> 3) & 7) << 3;

  int kIters = K >> 6;
  for (int kt = 0; kt < kIters; ++kt) {
    __syncthreads();
    short8 av[4];
#pragma unroll
    for (int t2 = 0; t2 < 4; ++t2) {
      int idx = (w * 4 + t2) * 512 + lane * 8;
      int r = idx >> 6, c = idx & 63;
      av[t2] = *(const short8*)(Ab + (size_t)r * K + kt * 64 + c);
    }
    float btmp[4][8];
    if (sel) {
#pragma unroll
      for (int p = 0; p < 4; ++p) {
        int k = p * 16 + krow;
        const float* bp = (const float*)B + (size_t)(brow0 + kt * 64 + k) * ldb + bcol0 + bn * 128 + ncol;
        float4 f0 = *(const float4*)bp;
        float4 f1 = *(const float4*)(bp + 4);
        btmp[p][0] = f0.x; btmp[p][1] = f0.y; btmp[p][2] = f0.z; btmp[p][3] = f0.w;
        btmp[p][4] = f1.x; btmp[p][5] = f1.y; btmp[p][6] = f1.z; btmp[p][7] = f1.w;
      }
    } else {
#pragma unroll
      for (int p = 0; p < 4; ++p) {
        int k = p * 16 + krow;
        const u16* bp = (const u16*)B + (size_t)(brow0 + kt * 64 + k) * ldb + bcol0 + bn * 128 + ncol;
#pragma unroll
        for (int j = 0; j < 8; ++j) btmp[p][j] = bf2f(bp[j]);
      }
    }
#pragma unroll
    for (int t2 = 0; t2 < 4; ++t2)
      *(short8*)&As[(w * 4 + t2) * 512 + lane * 8] = av[t2];
#pragma unroll
    for (int p = 0; p < 4; ++p) {
      int k = p * 16 + krow;
#pragma unroll
      for (int j = 0; j < 8; ++j)
        Bs[(ncol + j) * 64 + (k ^ swb)] = f2bf(btmp[p][j]);
    }
    __syncthreads();
#pragma unroll
    for (int ks = 0; ks < 2; ++ks) {
      short8 af[4], bfr[4];
#pragma unroll
      for (int mt = 0; mt < 4; mt++)
        af[mt] = *(const short8*)&As[(wm * 64 + mt * 16 + c16) * 64 + ks * 32 + quad * 8];
#pragma unroll
      for (int nt = 0; nt < 4; nt++) {
        int n = wn * 64 + nt * 16 + c16;
        int sw = ((n >> 3) & 7) << 3;
        bfr[nt] = *(const short8*)&Bs[n * 64 + ((ks * 32 + quad * 8) ^ sw)];
      }
#pragma unroll
      for (int mt = 0; mt < 4; mt++)
#pragma unroll
        for (int nt = 0; nt < 4; nt++)
          acc[mt][nt] = __builtin_amdgcn_mfma_f32_16x16x32_bf16(af[mt], bfr[nt], acc[mt][nt], 0, 0, 0);
    }
  }
  // epilogue: C layout col=lane&15, row=quad*4+reg
  int gm0 = bm * 128 + wm * 64;
  int gn0 = bn * 128 + wn * 64;
#pragma unroll
  for (int nt = 0; nt < 4; nt++) {
    int gn = gn0 + nt * 16 + c16;
    float bia = 0.f;
    if constexpr (EPI == 0 || EPI == 2) bia = ldx(bias, bcol0 + gn, sel);
    else if constexpr (EPI == 1 || EPI == 4) bia = ldx(bias, gn, sel);
#pragma unroll
    for (int mt = 0; mt < 4; mt++) {
#pragma unroll
      for (int r = 0; r < 4; r++) {
        int gm = gm0 + mt * 16 + quad * 4 + r;
        size_t o = (size_t)gm * ldc + gn;
        float v = acc[mt][nt][r] + bia;
        if constexpr (EPI == 0) {
          ((u16*)outp)[o] = f2bf(v);
        } else if constexpr (EPI == 1) {
          ((float*)outp)[o] = v + ldx(res, o, sel);
        } else if constexpr (EPI == 2) {
          float g = 0.5f * v * (1.f + tanhf(0.7978845608f * (v + 0.044715f * v * v * v)));
          ((u16*)outp)[o] = f2bf(g);
        } else if constexpr (EPI == 3) {
          ((float*)outp)[o] += v;
        } else {
          ((float*)outp)[o] += v;
        }
      }
    }
  }
}

// ---------------- flash attention, causal, bf16 MFMA ----------------
// qkvb: [2048][3072] bf16 (one batch); grid (qt=32, h=16); 256 thr = 4 waves,
// wave w handles q rows qt*64 + w*16 .. +15; kv tiles of 32 keys.
__global__ __launch_bounds__(256) void attn_mfma(const u16* __restrict__ qkvb,
                                                 u16* __restrict__ aout) {
  int qt = blockIdx.x, h = blockIdx.y;
  int tid = threadIdx.x, lane = tid & 63, w = tid >> 6;
  int quad = lane >> 4, c16 = lane & 15;
  __shared__ __align__(16) u16 Ks[32 * 64];      // [key][d]
  __shared__ __align__(16) u16 Vt[64 * 32];      // [d][key]
  __shared__ __align__(16) u16 Ps[4][16 * 32];   // per-wave [q][key]

  int qrow = qt * 64 + w * 16 + c16;
  size_t qoff = (size_t)qrow * 3072 + h * 64;
  short8 qf0 = *(const short8*)(qkvb + qoff + quad * 8);
  short8 qf1 = *(const short8*)(qkvb + qoff + 32 + quad * 8);

  float m_run[4], l_run[4];
  floatx4 zf = {0.f, 0.f, 0.f, 0.f};
  floatx4 oacc[4];
#pragma unroll
  for (int r = 0; r < 4; r++) { m_run[r] = -1e30f; l_run[r] = 0.f; }
#pragma unroll
  for (int c = 0; c < 4; c++) oacc[c] = zf;
  int q_reg[4];
#pragma unroll
  for (int r = 0; r < 4; r++) q_reg[r] = qt * 64 + w * 16 + quad * 4 + r;

  int nTiles = qt * 2 + 2;              // uniform across block (causal cover)
  int r32 = tid >> 3;                   // key row 0..31
  int cc8 = (tid & 7) * 8;              // d col 0..56
  for (int kt = 0; kt < nTiles; ++kt) {
    __syncthreads();
    size_t kbase = (size_t)(kt * 32 + r32) * 3072 + h * 64 + cc8;
    short8 kvec = *(const short8*)(qkvb + kbase + 1024);
    *(short8*)&Ks[r32 * 64 + cc8] = kvec;
    short8 vvec = *(const short8*)(qkvb + kbase + 2048);
#pragma unroll
    for (int j = 0; j < 8; j++) Vt[(cc8 + j) * 32 + r32] = (u16)vvec[j];
    __syncthreads();

    // S = Q K^T, two 16-key chunks
    floatx4 s[2];
#pragma unroll
    for (int n = 0; n < 2; n++) {
      short8 kf0 = *(const short8*)&Ks[(n * 16 + c16) * 64 + quad * 8];
      short8 kf1 = *(const short8*)&Ks[(n * 16 + c16) * 64 + 32 + quad * 8];
      floatx4 a = zf;
      a = __builtin_amdgcn_mfma_f32_16x16x32_bf16(qf0, kf0, a, 0, 0, 0);
      a = __builtin_amdgcn_mfma_f32_16x16x32_bf16(qf1, kf1, a, 0, 0, 0);
      s[n] = a;
    }
#pragma unroll
    for (int n = 0; n < 2; n++) {
      int kg = kt * 32 + n * 16 + c16;
#pragma unroll
      for (int r = 0; r < 4; r++) {
        float sv = s[n][r] * 0.125f;
        s[n][r] = (kg > q_reg[r]) ? -1e30f : sv;
      }
    }
    // row max across the 16 lanes of the quad
    float mt_[4];
#pragma unroll
    for (int r = 0; r < 4; r++) mt_[r] = fmaxf(s[0][r], s[1][r]);
#pragma unroll
    for (int off = 1; off < 16; off <<= 1)
#pragma unroll
      for (int r = 0; r < 4; r++) mt_[r] = fmaxf(mt_[r], __shfl_xor(mt_[r], off));
    float m_new[4], alpha[4], lsum[4];
#pragma unroll
    for (int r = 0; r < 4; r++) {
      m_new[r] = fmaxf(m_run[r], mt_[r]);
      alpha[r] = __expf(m_run[r] - m_new[r]);
      m_run[r] = m_new[r];
      lsum[r] = 0.f;
    }
#pragma unroll
    for (int n = 0; n < 2; n++)
#pragma unroll
      for (int r = 0; r < 4; r++) {
        float p = __expf(s[n][r] - m_new[r]);
        s[n][r] = p;
        lsum[r] += p;
      }
#pragma unroll
    for (int off = 1; off < 16; off <<= 1)
#pragma unroll
      for (int r = 0; r < 4; r++) lsum[r] += __shfl_xor(lsum[r], off);
#pragma unroll
    for (int r = 0; r < 4; r++) l_run[r] = l_run[r] * alpha[r] + lsum[r];
#pragma unroll
    for (int c = 0; c < 4; c++)
#pragma unroll
      for (int r = 0; r < 4; r++) oacc[c][r] *= alpha[r];

    // P (C-layout) -> per-wave LDS -> A-layout
    u16* pw = &Ps[w][0];
#pragma unroll
    for (int n = 0; n < 2; n++)
#pragma unroll
      for (int r = 0; r < 4; r++)
        pw[(quad * 4 + r) * 32 + n * 16 + c16] = f2bf(s[n][r]);
    __syncthreads();
    short8 pf = *(const short8*)&pw[c16 * 32 + quad * 8];
#pragma unroll
    for (int c = 0; c < 4; c++) {
      short8 vf = *(const short8*)&Vt[(c * 16 + c16) * 32 + quad * 8];
      oacc[c] = __builtin_amdgcn_mfma_f32_16x16x32_bf16(pf, vf, oacc[c], 0, 0, 0);
    }
  }
  size_t obase = (size_t)(qt * 64 + w * 16) * 1024 + h * 64;
#pragma unroll
  for (int r = 0; r < 4; r++) {
    float invl = 1.f / l_run[r];
#pragma unroll
    for (int c = 0; c < 4; c++)
      aout[obase + (size_t)(quad * 4 + r) * 1024 + c * 16 + c16] = f2bf(oacc[c][r] * invl);
  }
}

extern "C" void kernel_launch(void* const* d_in, const int* in_sizes, int n_in,
                              void* d_out, int out_size, void* d_ws, size_t ws_size,
                              hipStream_t stream) {
  const void* x        = d_in[0];
  const void* ln1_w    = d_in[1];
  const void* ln1_b    = d_in[2];
  const void* c_attn_w = d_in[3];
  const void* c_attn_b = d_in[4];
  const void* c_proj_w = d_in[5];
  const void* c_proj_b = d_in[6];
  const void* ln2_w    = d_in[7];
  const void* ln2_b    = d_in[8];
  const void* fc_w     = d_in[9];
  const void* fc_b     = d_in[10];
  const void* proj_w   = d_in[11];
  const void* proj_b   = d_in[12];

  char* ws = (char*)d_ws;
  // peak ws: 28 MiB + 4 B
  u16*   ln1b     = (u16*)(ws + 0);          // [4096][1024] bf16, dead after qkv gemms
  u16*   qkvb     = (u16*)(ws + 8388608);    // [2048][3072] bf16 per batch, [8,20) MiB
  u16*   attn_out = (u16*)(ws + 20971520);   // [4096][1024] bf16, [20,28) MiB
  u16*   ln2b     = (u16*)(ws + 0);          // [4096][1024] bf16 (reuses ln1b)
  u16*   h_c      = (u16*)(ws + 8388608);    // [4096][1024] bf16 per chunk (reuses qkvb)
  int*   selp     = (int*)(ws + 29360128);   // at 28 MiB
  float* x1       = (float*)d_out;           // [4096][1024] fp32; final output in place

  sniff_dtype<<<1, 256, 0, stream>>>(x, selp);

  // LN1 -> bf16
  ln_any<0><<<4096, 256, 0, stream>>>(x, ln1_w, ln1_b, selp, ln1b);

  // per batch: qkv = ln1b_batch @ c_attn_w + b (bf16), then MFMA flash attention
  for (int b = 0; b < 2; b++) {
    gemm_mfma<0><<<dim3(24, 16), 256, 0, stream>>>(ln1b + (size_t)b * 2048 * 1024,
                                                   c_attn_w, c_attn_b, nullptr, qkvb,
                                                   1024, 3072, 3072, 0, 0, selp);
    attn_mfma<<<dim3(32, 16), 256, 0, stream>>>(qkvb, attn_out + (size_t)b * 2048 * 1024);
  }

  // x1 = attn_out @ c_proj_w + c_proj_b + x  (fp32, into d_out)
  gemm_mfma<1><<<dim3(8, 32), 256, 0, stream>>>(attn_out, c_proj_w, c_proj_b, x, x1,
                                                1024, 1024, 1024, 0, 0, selp);

  // LN2 (reads fp32 x1) -> bf16
  ln_any<1><<<4096, 256, 0, stream>>>(x1, ln2_w, ln2_b, selp, ln2b);

  // MLP in 4 chunks of 1024: h_c = gelu(ln2b @ fc_w[:,c]); x1 += h_c @ proj_w[c,:] (+proj_b last)
  for (int c = 0; c < 4; c++) {
    gemm_mfma<2><<<dim3(8, 32), 256, 0, stream>>>(ln2b, fc_w, fc_b, nullptr, h_c,
                                                  1024, 4096, 1024, 0, c * 1024, selp);
    if (c < 3)
      gemm_mfma<3><<<dim3(8, 32), 256, 0, stream>>>(h_c, proj_w, nullptr, nullptr, x1,
                                                    1024, 1024, 1024, c * 1024, 0, selp);
    else
      gemm_mfma<4><<<dim3(8, 32), 256, 0, stream>>>(h_c, proj_w, proj_b, nullptr, x1,
                                                    1024, 1024, 1024, c * 1024, 0, selp);
  }
}

// Round 9
// 859.654 us; speedup vs baseline: 8.9152x; 2.4737x over previous
//
#include <hip/hip_runtime.h>

typedef unsigned short u16;
typedef __attribute__((ext_vector_type(8))) short short8;
typedef __attribute__((ext_vector_type(4))) float floatx4;

__device__ __forceinline__ float bf2f(u16 u) {
  unsigned int v = ((unsigned int)u) << 16;
  return __builtin_bit_cast(float, v);
}
__device__ __forceinline__ u16 f2bf(float f) {
  unsigned int u = __builtin_bit_cast(unsigned int, f);
  u += 0x7FFFu + ((u >> 16) & 1u);
  return (u16)(u >> 16);
}

// ---------------- layernorm (Bessel std, eps added to std) -> bf16 ----------------
// input always fp32 (external x or fp32 workspace)
__global__ __launch_bounds__(256) void ln_f32(const float* __restrict__ xin,
                                              const float* __restrict__ wgt,
                                              const float* __restrict__ bia,
                                              u16* __restrict__ out) {
  int row = blockIdx.x, t = threadIdx.x;
  const float* xr = xin + (size_t)row * 1024 + t * 4;
  float4 f = *(const float4*)xr;
  float v[4] = {f.x, f.y, f.z, f.w};
  float s1 = v[0] + v[1] + v[2] + v[3];
  float s2 = v[0] * v[0] + v[1] * v[1] + v[2] * v[2] + v[3] * v[3];
#pragma unroll
  for (int off = 32; off; off >>= 1) {
    s1 += __shfl_down(s1, off);
    s2 += __shfl_down(s2, off);
  }
  __shared__ float red[8];
  int lane = t & 63, w = t >> 6;
  if (lane == 0) { red[w] = s1; red[4 + w] = s2; }
  __syncthreads();
  s1 = red[0] + red[1] + red[2] + red[3];
  s2 = red[4] + red[5] + red[6] + red[7];
  float mean = s1 * (1.f / 1024.f);
  float var = (s2 - 1024.f * mean * mean) * (1.f / 1023.f);
  var = var < 0.f ? 0.f : var;
  float inv = 1.f / (sqrtf(var) + 1e-5f);
  float4 wv = *(const float4*)(wgt + t * 4);
  float4 bv = *(const float4*)(bia + t * 4);
  float wa[4] = {wv.x, wv.y, wv.z, wv.w};
  float ba[4] = {bv.x, bv.y, bv.z, bv.w};
#pragma unroll
  for (int j = 0; j < 4; j++)
    out[(size_t)row * 1024 + t * 4 + j] = f2bf(wa[j] * ((v[j] - mean) * inv) + ba[j]);
}

// ------- MFMA GEMM: C = A(bf16,[M][K]) @ B(fp32,[K][N] ldb, +brow0,+bcol0) -------
// EPI 0: bf16 out = v + bias[bcol0+gn]            (qkv)
// EPI 1: f32 out = v + bias[gn] + res[o]          (c_proj + residual x)
// EPI 2: bf16 out = gelu(v + bias[bcol0+gn])      (fc)
// EPI 3: f32 out += v                              (proj chunk)
// EPI 4: f32 out += v + bias[gn]                   (last proj chunk)
template <int EPI>
__global__ __launch_bounds__(256) void gemm_mfma(const u16* __restrict__ A,
                                                 const float* __restrict__ B,
                                                 const float* __restrict__ bias,
                                                 const float* __restrict__ res,
                                                 void* __restrict__ outp,
                                                 int K, int ldb, int ldc,
                                                 int brow0, int bcol0) {
  __shared__ __align__(16) u16 As[128 * 64];   // [m][k]
  __shared__ __align__(16) u16 Bs[128 * 64];   // [n][k ^ sw(n)]
  int tid = threadIdx.x;
  int lane = tid & 63, w = tid >> 6;
  int quad = lane >> 4, c16 = lane & 15;
  int wm = w >> 1, wn = w & 1;
  int bn = blockIdx.x, bm = blockIdx.y;
  const u16* Ab = A + (size_t)bm * 128 * K;

  floatx4 zf = {0.f, 0.f, 0.f, 0.f};
  floatx4 acc[4][4];
#pragma unroll
  for (int i = 0; i < 4; i++)
#pragma unroll
    for (int j = 0; j < 4; j++) acc[i][j] = zf;

  int krow = tid >> 4;          // 0..15
  int ncol = (tid & 15) * 8;    // 0..120
  int swb = ((ncol >> 3) & 7) << 3;

  int kIters = K >> 6;
  for (int kt = 0; kt < kIters; ++kt) {
    __syncthreads();
    short8 av[4];
#pragma unroll
    for (int t2 = 0; t2 < 4; ++t2) {
      int idx = (w * 4 + t2) * 512 + lane * 8;
      int r = idx >> 6, c = idx & 63;
      av[t2] = *(const short8*)(Ab + (size_t)r * K + kt * 64 + c);
    }
    float btmp[4][8];
#pragma unroll
    for (int p = 0; p < 4; ++p) {
      int k = p * 16 + krow;
      const float* bp = B + (size_t)(brow0 + kt * 64 + k) * ldb + bcol0 + bn * 128 + ncol;
      float4 f0 = *(const float4*)bp;
      float4 f1 = *(const float4*)(bp + 4);
      btmp[p][0] = f0.x; btmp[p][1] = f0.y; btmp[p][2] = f0.z; btmp[p][3] = f0.w;
      btmp[p][4] = f1.x; btmp[p][5] = f1.y; btmp[p][6] = f1.z; btmp[p][7] = f1.w;
    }
#pragma unroll
    for (int t2 = 0; t2 < 4; ++t2)
      *(short8*)&As[(w * 4 + t2) * 512 + lane * 8] = av[t2];
#pragma unroll
    for (int p = 0; p < 4; ++p) {
      int k = p * 16 + krow;
#pragma unroll
      for (int j = 0; j < 8; ++j)
        Bs[(ncol + j) * 64 + (k ^ swb)] = f2bf(btmp[p][j]);
    }
    __syncthreads();
#pragma unroll
    for (int ks = 0; ks < 2; ++ks) {
      short8 af[4], bfr[4];
#pragma unroll
      for (int mt = 0; mt < 4; mt++)
        af[mt] = *(const short8*)&As[(wm * 64 + mt * 16 + c16) * 64 + ks * 32 + quad * 8];
#pragma unroll
      for (int nt = 0; nt < 4; nt++) {
        int n = wn * 64 + nt * 16 + c16;
        int sw = ((n >> 3) & 7) << 3;
        bfr[nt] = *(const short8*)&Bs[n * 64 + ((ks * 32 + quad * 8) ^ sw)];
      }
#pragma unroll
      for (int mt = 0; mt < 4; mt++)
#pragma unroll
        for (int nt = 0; nt < 4; nt++)
          acc[mt][nt] = __builtin_amdgcn_mfma_f32_16x16x32_bf16(af[mt], bfr[nt], acc[mt][nt], 0, 0, 0);
    }
  }
  // epilogue: C layout col=lane&15, row=quad*4+reg
  int gm0 = bm * 128 + wm * 64;
  int gn0 = bn * 128 + wn * 64;
#pragma unroll
  for (int nt = 0; nt < 4; nt++) {
    int gn = gn0 + nt * 16 + c16;
    float bia = 0.f;
    if constexpr (EPI == 0 || EPI == 2) bia = bias[bcol0 + gn];
    else if constexpr (EPI == 1 || EPI == 4) bia = bias[gn];
#pragma unroll
    for (int mt = 0; mt < 4; mt++) {
#pragma unroll
      for (int r = 0; r < 4; r++) {
        int gm = gm0 + mt * 16 + quad * 4 + r;
        size_t o = (size_t)gm * ldc + gn;
        float v = acc[mt][nt][r] + bia;
        if constexpr (EPI == 0) {
          ((u16*)outp)[o] = f2bf(v);
        } else if constexpr (EPI == 1) {
          ((float*)outp)[o] = v + res[o];
        } else if constexpr (EPI == 2) {
          float g = 0.5f * v * (1.f + tanhf(0.7978845608f * (v + 0.044715f * v * v * v)));
          ((u16*)outp)[o] = f2bf(g);
        } else {
          ((float*)outp)[o] += v;
        }
      }
    }
  }
}

// ---------------- flash attention, causal, bf16 MFMA ----------------
// qkvb: [2048][3072] bf16 (one batch); grid (qt=32, h=16); 4 waves, 16 q-rows each
__global__ __launch_bounds__(256) void attn_mfma(const u16* __restrict__ qkvb,
                                                 u16* __restrict__ aout) {
  int qt = blockIdx.x, h = blockIdx.y;
  int tid = threadIdx.x, lane = tid & 63, w = tid >> 6;
  int quad = lane >> 4, c16 = lane & 15;
  __shared__ __align__(16) u16 Ks[32 * 64];      // [key][d]
  __shared__ __align__(16) u16 Vt[64 * 32];      // [d][key]
  __shared__ __align__(16) u16 Ps[4][16 * 32];   // per-wave [q][key]

  int qrow = qt * 64 + w * 16 + c16;
  size_t qoff = (size_t)qrow * 3072 + h * 64;
  short8 qf0 = *(const short8*)(qkvb + qoff + quad * 8);
  short8 qf1 = *(const short8*)(qkvb + qoff + 32 + quad * 8);

  float m_run[4], l_run[4];
  floatx4 zf = {0.f, 0.f, 0.f, 0.f};
  floatx4 oacc[4];
#pragma unroll
  for (int r = 0; r < 4; r++) { m_run[r] = -1e30f; l_run[r] = 0.f; }
#pragma unroll
  for (int c = 0; c < 4; c++) oacc[c] = zf;
  int q_reg[4];
#pragma unroll
  for (int r = 0; r < 4; r++) q_reg[r] = qt * 64 + w * 16 + quad * 4 + r;

  int nTiles = qt * 2 + 2;              // uniform across block (causal cover)
  int r32 = tid >> 3;                   // key row 0..31
  int cc8 = (tid & 7) * 8;              // d col 0..56
  for (int kt = 0; kt < nTiles; ++kt) {
    __syncthreads();
    size_t kbase = (size_t)(kt * 32 + r32) * 3072 + h * 64 + cc8;
    short8 kvec = *(const short8*)(qkvb + kbase + 1024);
    *(short8*)&Ks[r32 * 64 + cc8] = kvec;
    short8 vvec = *(const short8*)(qkvb + kbase + 2048);
#pragma unroll
    for (int j = 0; j < 8; j++) Vt[(cc8 + j) * 32 + r32] = (u16)vvec[j];
    __syncthreads();

    floatx4 s[2];
#pragma unroll
    for (int n = 0; n < 2; n++) {
      short8 kf0 = *(const short8*)&Ks[(n * 16 + c16) * 64 + quad * 8];
      short8 kf1 = *(const short8*)&Ks[(n * 16 + c16) * 64 + 32 + quad * 8];
      floatx4 a = zf;
      a = __builtin_amdgcn_mfma_f32_16x16x32_bf16(qf0, kf0, a, 0, 0, 0);
      a = __builtin_amdgcn_mfma_f32_16x16x32_bf16(qf1, kf1, a, 0, 0, 0);
      s[n] = a;
    }
#pragma unroll
    for (int n = 0; n < 2; n++) {
      int kg = kt * 32 + n * 16 + c16;
#pragma unroll
      for (int r = 0; r < 4; r++) {
        float sv = s[n][r] * 0.125f;
        s[n][r] = (kg > q_reg[r]) ? -1e30f : sv;
      }
    }
    float mt_[4];
#pragma unroll
    for (int r = 0; r < 4; r++) mt_[r] = fmaxf(s[0][r], s[1][r]);
#pragma unroll
    for (int off = 1; off < 16; off <<= 1)
#pragma unroll
      for (int r = 0; r < 4; r++) mt_[r] = fmaxf(mt_[r], __shfl_xor(mt_[r], off));
    float m_new[4], alpha[4], lsum[4];
#pragma unroll
    for (int r = 0; r < 4; r++) {
      m_new[r] = fmaxf(m_run[r], mt_[r]);
      alpha[r] = __expf(m_run[r] - m_new[r]);
      m_run[r] = m_new[r];
      lsum[r] = 0.f;
    }
#pragma unroll
    for (int n = 0; n < 2; n++)
#pragma unroll
      for (int r = 0; r < 4; r++) {
        float p = __expf(s[n][r] - m_new[r]);
        s[n][r] = p;
        lsum[r] += p;
      }
#pragma unroll
    for (int off = 1; off < 16; off <<= 1)
#pragma unroll
      for (int r = 0; r < 4; r++) lsum[r] += __shfl_xor(lsum[r], off);
#pragma unroll
    for (int r = 0; r < 4; r++) l_run[r] = l_run[r] * alpha[r] + lsum[r];
#pragma unroll
    for (int c = 0; c < 4; c++)
#pragma unroll
      for (int r = 0; r < 4; r++) oacc[c][r] *= alpha[r];

    u16* pw = &Ps[w][0];
#pragma unroll
    for (int n = 0; n < 2; n++)
#pragma unroll
      for (int r = 0; r < 4; r++)
        pw[(quad * 4 + r) * 32 + n * 16 + c16] = f2bf(s[n][r]);
    __syncthreads();
    short8 pf = *(const short8*)&pw[c16 * 32 + quad * 8];
#pragma unroll
    for (int c = 0; c < 4; c++) {
      short8 vf = *(const short8*)&Vt[(c * 16 + c16) * 32 + quad * 8];
      oacc[c] = __builtin_amdgcn_mfma_f32_16x16x32_bf16(pf, vf, oacc[c], 0, 0, 0);
    }
  }
  size_t obase = (size_t)(qt * 64 + w * 16) * 1024 + h * 64;
#pragma unroll
  for (int r = 0; r < 4; r++) {
    float invl = 1.f / l_run[r];
#pragma unroll
    for (int c = 0; c < 4; c++)
      aout[obase + (size_t)(quad * 4 + r) * 1024 + c * 16 + c16] = f2bf(oacc[c][r] * invl);
  }
}

extern "C" void kernel_launch(void* const* d_in, const int* in_sizes, int n_in,
                              void* d_out, int out_size, void* d_ws, size_t ws_size,
                              hipStream_t stream) {
  const float* x        = (const float*)d_in[0];
  const float* ln1_w    = (const float*)d_in[1];
  const float* ln1_b    = (const float*)d_in[2];
  const float* c_attn_w = (const float*)d_in[3];
  const float* c_attn_b = (const float*)d_in[4];
  const float* c_proj_w = (const float*)d_in[5];
  const float* c_proj_b = (const float*)d_in[6];
  const float* ln2_w    = (const float*)d_in[7];
  const float* ln2_b    = (const float*)d_in[8];
  const float* fc_w     = (const float*)d_in[9];
  const float* fc_b     = (const float*)d_in[10];
  const float* proj_w   = (const float*)d_in[11];
  const float* proj_b   = (const float*)d_in[12];

  char* ws = (char*)d_ws;
  // peak ws: 28 MiB
  u16*   ln1b     = (u16*)(ws + 0);          // [4096][1024] bf16, dead after qkv gemms
  u16*   qkvb     = (u16*)(ws + 8388608);    // [2048][3072] bf16 per batch, [8,20) MiB
  u16*   attn_out = (u16*)(ws + 20971520);   // [4096][1024] bf16, [20,28) MiB
  u16*   ln2b     = (u16*)(ws + 0);          // [4096][1024] bf16 (reuses ln1b)
  u16*   h_c      = (u16*)(ws + 8388608);    // [4096][1024] bf16 per chunk (reuses qkvb)
  float* x1       = (float*)d_out;           // [4096][1024] fp32; final output in place

  // LN1 -> bf16
  ln_f32<<<4096, 256, 0, stream>>>(x, ln1_w, ln1_b, ln1b);

  // per batch: qkv = ln1b_batch @ c_attn_w + b (bf16), then MFMA flash attention
  for (int b = 0; b < 2; b++) {
    gemm_mfma<0><<<dim3(24, 16), 256, 0, stream>>>(ln1b + (size_t)b * 2048 * 1024,
                                                   c_attn_w, c_attn_b, nullptr, qkvb,
                                                   1024, 3072, 3072, 0, 0);
    attn_mfma<<<dim3(32, 16), 256, 0, stream>>>(qkvb, attn_out + (size_t)b * 2048 * 1024);
  }

  // x1 = attn_out @ c_proj_w + c_proj_b + x  (fp32, into d_out)
  gemm_mfma<1><<<dim3(8, 32), 256, 0, stream>>>(attn_out, c_proj_w, c_proj_b, x, x1,
                                                1024, 1024, 1024, 0, 0);

  // LN2 (reads fp32 x1) -> bf16
  ln_f32<<<4096, 256, 0, stream>>>(x1, ln2_w, ln2_b, ln2b);

  // MLP in 4 chunks of 1024: h_c = gelu(ln2b @ fc_w[:,c]); x1 += h_c @ proj_w[c,:] (+proj_b last)
  for (int c = 0; c < 4; c++) {
    gemm_mfma<2><<<dim3(8, 32), 256, 0, stream>>>(ln2b, fc_w, fc_b, nullptr, h_c,
                                                  1024, 4096, 1024, 0, c * 1024);
    if (c < 3)
      gemm_mfma<3><<<dim3(8, 32), 256, 0, stream>>>(h_c, proj_w, nullptr, nullptr, x1,
                                                    1024, 1024, 1024, c * 1024, 0);
    else
      gemm_mfma<4><<<dim3(8, 32), 256, 0, stream>>>(h_c, proj_w, proj_b, nullptr, x1,
                                                    1024, 1024, 1024, c * 1024, 0);
  }
}

// Round 10
// 775.526 us; speedup vs baseline: 9.8823x; 1.1085x over previous
//
#include <hip/hip_runtime.h>

typedef unsigned short u16;
typedef __attribute__((ext_vector_type(8))) short short8;
typedef __attribute__((ext_vector_type(4))) float floatx4;

__device__ __forceinline__ float bf2f(u16 u) {
  unsigned int v = ((unsigned int)u) << 16;
  return __builtin_bit_cast(float, v);
}
__device__ __forceinline__ u16 f2bf(float f) {
  unsigned int u = __builtin_bit_cast(unsigned int, f);
  u += 0x7FFFu + ((u >> 16) & 1u);
  return (u16)(u >> 16);
}
__device__ __forceinline__ void gload_lds16(const void* g, void* l) {
  __builtin_amdgcn_global_load_lds(
      (const __attribute__((address_space(1))) unsigned int*)g,
      (__attribute__((address_space(3))) unsigned int*)l, 16, 0, 0);
}

// ---------- transpose+convert: in fp32 [K][N] -> out bf16 [N][K] ----------
__global__ __launch_bounds__(256) void transpose_f32_bf16(const float* __restrict__ in,
                                                          u16* __restrict__ out,
                                                          int K, int N) {
  __shared__ float tile[32][33];
  int n0 = blockIdx.x * 32, k0 = blockIdx.y * 32;
  int tx = threadIdx.x & 31, ty = threadIdx.x >> 5;  // ty 0..7
#pragma unroll
  for (int i = 0; i < 4; i++) {
    int r = ty + i * 8;
    tile[r][tx] = in[(size_t)(k0 + r) * N + n0 + tx];
  }
  __syncthreads();
#pragma unroll
  for (int i = 0; i < 4; i++) {
    int r = ty + i * 8;
    out[(size_t)(n0 + r) * K + k0 + tx] = f2bf(tile[tx][r]);
  }
}

// ---------------- layernorm (Bessel std, eps added to std) -> bf16 ----------------
__global__ __launch_bounds__(256) void ln_f32(const float* __restrict__ xin,
                                              const float* __restrict__ wgt,
                                              const float* __restrict__ bia,
                                              u16* __restrict__ out) {
  int row = blockIdx.x, t = threadIdx.x;
  const float* xr = xin + (size_t)row * 1024 + t * 4;
  float4 f = *(const float4*)xr;
  float v[4] = {f.x, f.y, f.z, f.w};
  float s1 = v[0] + v[1] + v[2] + v[3];
  float s2 = v[0] * v[0] + v[1] * v[1] + v[2] * v[2] + v[3] * v[3];
#pragma unroll
  for (int off = 32; off; off >>= 1) {
    s1 += __shfl_down(s1, off);
    s2 += __shfl_down(s2, off);
  }
  __shared__ float red[8];
  int lane = t & 63, w = t >> 6;
  if (lane == 0) { red[w] = s1; red[4 + w] = s2; }
  __syncthreads();
  s1 = red[0] + red[1] + red[2] + red[3];
  s2 = red[4] + red[5] + red[6] + red[7];
  float mean = s1 * (1.f / 1024.f);
  float var = (s2 - 1024.f * mean * mean) * (1.f / 1023.f);
  var = var < 0.f ? 0.f : var;
  float inv = 1.f / (sqrtf(var) + 1e-5f);
  float4 wv = *(const float4*)(wgt + t * 4);
  float4 bv = *(const float4*)(bia + t * 4);
  float wa[4] = {wv.x, wv.y, wv.z, wv.w};
  float ba[4] = {bv.x, bv.y, bv.z, bv.w};
#pragma unroll
  for (int j = 0; j < 4; j++)
    out[(size_t)row * 1024 + t * 4 + j] = f2bf(wa[j] * ((v[j] - mean) * inv) + ba[j]);
}

// ------- m97-style MFMA GEMM: C = A(bf16,[M][K]) @ Bt(bf16,[N][K])^T -------
// A,Bt row stride == K. global_load_lds width-16 staging for both operands.
// EPI 0: bf16 out = v + bias[gn]          (qkv)
// EPI 1: f32 out = v + bias[gn] + res[o]  (c_proj + residual)
// EPI 2: bf16 out = gelu(v + bias[gn])    (fc)
// EPI 3: f32 out += v                      (proj chunk)
// EPI 4: f32 out += v + bias[gn]           (last proj chunk)
template <int EPI>
__global__ __launch_bounds__(256) void gemm_bt(const u16* __restrict__ A,
                                               const u16* __restrict__ Bt,
                                               const float* __restrict__ bias,
                                               const float* __restrict__ res,
                                               void* __restrict__ outp,
                                               int ldc, int K) {
  __shared__ __align__(16) u16 As[128 * 64];   // [m][k]
  __shared__ __align__(16) u16 Bs[128 * 64];   // [n][k]
  int tid = threadIdx.x;
  int lane = tid & 63, w = tid >> 6;
  int quad = lane >> 4, c16 = lane & 15;
  int wm = w >> 1, wn = w & 1;
  int bn = blockIdx.x, bm = blockIdx.y;
  const u16* Ab = A + (size_t)bm * 128 * K;
  const u16* Bb = Bt + (size_t)bn * 128 * K;

  floatx4 zf = {0.f, 0.f, 0.f, 0.f};
  floatx4 acc[4][4];
#pragma unroll
  for (int i = 0; i < 4; i++)
#pragma unroll
    for (int j = 0; j < 4; j++) acc[i][j] = zf;

  int kIters = K >> 6;
  for (int kt = 0; kt < kIters; ++kt) {
    __syncthreads();
    const u16* Abase = Ab + kt * 64;
    const u16* Bbase = Bb + kt * 64;
#pragma unroll
    for (int t2 = 0; t2 < 4; ++t2) {
      int chunk = w * 4 + t2;
      int idx = chunk * 512 + lane * 8;
      int r = idx >> 6, cc = idx & 63;
      gload_lds16(Abase + (size_t)r * K + cc, &As[chunk * 512]);
      gload_lds16(Bbase + (size_t)r * K + cc, &Bs[chunk * 512]);
    }
    __syncthreads();
#pragma unroll
    for (int ks = 0; ks < 2; ++ks) {
      short8 af[4], bfr[4];
#pragma unroll
      for (int mt = 0; mt < 4; mt++)
        af[mt] = *(const short8*)&As[(wm * 64 + mt * 16 + c16) * 64 + ks * 32 + quad * 8];
#pragma unroll
      for (int nt = 0; nt < 4; nt++)
        bfr[nt] = *(const short8*)&Bs[(wn * 64 + nt * 16 + c16) * 64 + ks * 32 + quad * 8];
#pragma unroll
      for (int mt = 0; mt < 4; mt++)
#pragma unroll
        for (int nt = 0; nt < 4; nt++)
          acc[mt][nt] = __builtin_amdgcn_mfma_f32_16x16x32_bf16(af[mt], bfr[nt], acc[mt][nt], 0, 0, 0);
    }
  }
  // epilogue: C layout col=lane&15, row=quad*4+reg
  int gm0 = bm * 128 + wm * 64;
  int gn0 = bn * 128 + wn * 64;
#pragma unroll
  for (int nt = 0; nt < 4; nt++) {
    int gn = gn0 + nt * 16 + c16;
    float bia = 0.f;
    if constexpr (EPI != 3) bia = bias[gn];
#pragma unroll
    for (int mt = 0; mt < 4; mt++) {
#pragma unroll
      for (int r = 0; r < 4; r++) {
        int gm = gm0 + mt * 16 + quad * 4 + r;
        size_t o = (size_t)gm * ldc + gn;
        float v = acc[mt][nt][r] + bia;
        if constexpr (EPI == 0) {
          ((u16*)outp)[o] = f2bf(v);
        } else if constexpr (EPI == 1) {
          ((float*)outp)[o] = v + res[o];
        } else if constexpr (EPI == 2) {
          float g = 0.5f * v * (1.f + tanhf(0.7978845608f * (v + 0.044715f * v * v * v)));
          ((u16*)outp)[o] = f2bf(g);
        } else {
          ((float*)outp)[o] += v;
        }
      }
    }
  }
}

// ---------------- flash attention, causal, bf16 MFMA (unchanged from R9) ----------------
__global__ __launch_bounds__(256) void attn_mfma(const u16* __restrict__ qkvb,
                                                 u16* __restrict__ aout) {
  int qt = blockIdx.x, h = blockIdx.y;
  int tid = threadIdx.x, lane = tid & 63, w = tid >> 6;
  int quad = lane >> 4, c16 = lane & 15;
  __shared__ __align__(16) u16 Ks[32 * 64];
  __shared__ __align__(16) u16 Vt[64 * 32];
  __shared__ __align__(16) u16 Ps[4][16 * 32];

  int qrow = qt * 64 + w * 16 + c16;
  size_t qoff = (size_t)qrow * 3072 + h * 64;
  short8 qf0 = *(const short8*)(qkvb + qoff + quad * 8);
  short8 qf1 = *(const short8*)(qkvb + qoff + 32 + quad * 8);

  float m_run[4], l_run[4];
  floatx4 zf = {0.f, 0.f, 0.f, 0.f};
  floatx4 oacc[4];
#pragma unroll
  for (int r = 0; r < 4; r++) { m_run[r] = -1e30f; l_run[r] = 0.f; }
#pragma unroll
  for (int c = 0; c < 4; c++) oacc[c] = zf;
  int q_reg[4];
#pragma unroll
  for (int r = 0; r < 4; r++) q_reg[r] = qt * 64 + w * 16 + quad * 4 + r;

  int nTiles = qt * 2 + 2;
  int r32 = tid >> 3;
  int cc8 = (tid & 7) * 8;
  for (int kt = 0; kt < nTiles; ++kt) {
    __syncthreads();
    size_t kbase = (size_t)(kt * 32 + r32) * 3072 + h * 64 + cc8;
    short8 kvec = *(const short8*)(qkvb + kbase + 1024);
    *(short8*)&Ks[r32 * 64 + cc8] = kvec;
    short8 vvec = *(const short8*)(qkvb + kbase + 2048);
#pragma unroll
    for (int j = 0; j < 8; j++) Vt[(cc8 + j) * 32 + r32] = (u16)vvec[j];
    __syncthreads();

    floatx4 s[2];
#pragma unroll
    for (int n = 0; n < 2; n++) {
      short8 kf0 = *(const short8*)&Ks[(n * 16 + c16) * 64 + quad * 8];
      short8 kf1 = *(const short8*)&Ks[(n * 16 + c16) * 64 + 32 + quad * 8];
      floatx4 a = zf;
      a = __builtin_amdgcn_mfma_f32_16x16x32_bf16(qf0, kf0, a, 0, 0, 0);
      a = __builtin_amdgcn_mfma_f32_16x16x32_bf16(qf1, kf1, a, 0, 0, 0);
      s[n] = a;
    }
#pragma unroll
    for (int n = 0; n < 2; n++) {
      int kg = kt * 32 + n * 16 + c16;
#pragma unroll
      for (int r = 0; r < 4; r++) {
        float sv = s[n][r] * 0.125f;
        s[n][r] = (kg > q_reg[r]) ? -1e30f : sv;
      }
    }
    float mt_[4];
#pragma unroll
    for (int r = 0; r < 4; r++) mt_[r] = fmaxf(s[0][r], s[1][r]);
#pragma unroll
    for (int off = 1; off < 16; off <<= 1)
#pragma unroll
      for (int r = 0; r < 4; r++) mt_[r] = fmaxf(mt_[r], __shfl_xor(mt_[r], off));
    float m_new[4], alpha[4], lsum[4];
#pragma unroll
    for (int r = 0; r < 4; r++) {
      m_new[r] = fmaxf(m_run[r], mt_[r]);
      alpha[r] = __expf(m_run[r] - m_new[r]);
      m_run[r] = m_new[r];
      lsum[r] = 0.f;
    }
#pragma unroll
    for (int n = 0; n < 2; n++)
#pragma unroll
      for (int r = 0; r < 4; r++) {
        float p = __expf(s[n][r] - m_new[r]);
        s[n][r] = p;
        lsum[r] += p;
      }
#pragma unroll
    for (int off = 1; off < 16; off <<= 1)
#pragma unroll
      for (int r = 0; r < 4; r++) lsum[r] += __shfl_xor(lsum[r], off);
#pragma unroll
    for (int r = 0; r < 4; r++) l_run[r] = l_run[r] * alpha[r] + lsum[r];
#pragma unroll
    for (int c = 0; c < 4; c++)
#pragma unroll
      for (int r = 0; r < 4; r++) oacc[c][r] *= alpha[r];

    u16* pw = &Ps[w][0];
#pragma unroll
    for (int n = 0; n < 2; n++)
#pragma unroll
      for (int r = 0; r < 4; r++)
        pw[(quad * 4 + r) * 32 + n * 16 + c16] = f2bf(s[n][r]);
    __syncthreads();
    short8 pf = *(const short8*)&pw[c16 * 32 + quad * 8];
#pragma unroll
    for (int c = 0; c < 4; c++) {
      short8 vf = *(const short8*)&Vt[(c * 16 + c16) * 32 + quad * 8];
      oacc[c] = __builtin_amdgcn_mfma_f32_16x16x32_bf16(pf, vf, oacc[c], 0, 0, 0);
    }
  }
  size_t obase = (size_t)(qt * 64 + w * 16) * 1024 + h * 64;
#pragma unroll
  for (int r = 0; r < 4; r++) {
    float invl = 1.f / l_run[r];
#pragma unroll
    for (int c = 0; c < 4; c++)
      aout[obase + (size_t)(quad * 4 + r) * 1024 + c * 16 + c16] = f2bf(oacc[c][r] * invl);
  }
}

extern "C" void kernel_launch(void* const* d_in, const int* in_sizes, int n_in,
                              void* d_out, int out_size, void* d_ws, size_t ws_size,
                              hipStream_t stream) {
  const float* x        = (const float*)d_in[0];
  const float* ln1_w    = (const float*)d_in[1];
  const float* ln1_b    = (const float*)d_in[2];
  const float* c_attn_w = (const float*)d_in[3];
  const float* c_attn_b = (const float*)d_in[4];
  const float* c_proj_w = (const float*)d_in[5];
  const float* c_proj_b = (const float*)d_in[6];
  const float* ln2_w    = (const float*)d_in[7];
  const float* ln2_b    = (const float*)d_in[8];
  const float* fc_w     = (const float*)d_in[9];
  const float* fc_b     = (const float*)d_in[10];
  const float* proj_w   = (const float*)d_in[11];
  const float* proj_b   = (const float*)d_in[12];

  char* ws = (char*)d_ws;
  // ---- phase 1 layout (peak = 28 MiB exactly) ----
  u16* wt_attn   = (u16*)(ws + 0);          // [3072][1024] bf16, 6 MiB
  u16* wt_cproj  = (u16*)(ws + 6291456);    // [1024][1024] bf16, 2 MiB
  u16* ln1b      = (u16*)(ws + 8388608);    // [2048][1024] bf16 per batch, 4 MiB
  u16* qkvb      = (u16*)(ws + 12582912);   // [2048][3072] bf16 per batch, 12 MiB
  u16* attn_outb = (u16*)(ws + 25165824);   // [2048][1024] bf16 per batch, 4 MiB (ends 28 MiB)
  // ---- phase 2 layout (reuses everything) ----
  u16* wt_fc     = (u16*)(ws + 0);          // [4096][1024] bf16, 8 MiB
  u16* ln2b      = (u16*)(ws + 8388608);    // [4096][1024] bf16, 8 MiB
  u16* h_c       = (u16*)(ws + 16777216);   // [4096][1024] bf16 per chunk, 8 MiB
  u16* projT_c   = (u16*)(ws + 25165824);   // [1024][1024] bf16 per chunk, 2 MiB
  float* x1      = (float*)d_out;           // [4096][1024] fp32; final out in place

  // phase 0: cache attention-phase weights as bf16 [N][K]
  transpose_f32_bf16<<<dim3(96, 32), 256, 0, stream>>>(c_attn_w, wt_attn, 1024, 3072);
  transpose_f32_bf16<<<dim3(32, 32), 256, 0, stream>>>(c_proj_w, wt_cproj, 1024, 1024);

  // phase 1: per batch LN1 -> qkv -> attention -> cproj(+residual)
  for (int b = 0; b < 2; b++) {
    size_t boff = (size_t)b * 2048 * 1024;
    ln_f32<<<2048, 256, 0, stream>>>(x + boff, ln1_w, ln1_b, ln1b);
    gemm_bt<0><<<dim3(24, 16), 256, 0, stream>>>(ln1b, wt_attn, c_attn_b, nullptr,
                                                 qkvb, 3072, 1024);
    attn_mfma<<<dim3(32, 16), 256, 0, stream>>>(qkvb, attn_outb);
    gemm_bt<1><<<dim3(8, 16), 256, 0, stream>>>(attn_outb, wt_cproj, c_proj_b,
                                                x + boff, x1 + boff, 1024, 1024);
  }

  // phase 2: MLP. cache fc weights; proj chunk transposed per iteration.
  transpose_f32_bf16<<<dim3(128, 32), 256, 0, stream>>>(fc_w, wt_fc, 1024, 4096);
  ln_f32<<<4096, 256, 0, stream>>>(x1, ln2_w, ln2_b, ln2b);
  for (int c = 0; c < 4; c++) {
    transpose_f32_bf16<<<dim3(32, 32), 256, 0, stream>>>(proj_w + (size_t)c * 1024 * 1024,
                                                         projT_c, 1024, 1024);
    gemm_bt<2><<<dim3(8, 32), 256, 0, stream>>>(ln2b, wt_fc + (size_t)c * 1024 * 1024,
                                                fc_b + c * 1024, nullptr, h_c, 1024, 1024);
    if (c < 3)
      gemm_bt<3><<<dim3(8, 32), 256, 0, stream>>>(h_c, projT_c, nullptr, nullptr,
                                                  x1, 1024, 1024);
    else
      gemm_bt<4><<<dim3(8, 32), 256, 0, stream>>>(h_c, projT_c, proj_b, nullptr,
                                                  x1, 1024, 1024);
  }
}

// Round 11
// 651.660 us; speedup vs baseline: 11.7607x; 1.1901x over previous
//
#include <hip/hip_runtime.h>

typedef unsigned short u16;
typedef __attribute__((ext_vector_type(8))) short short8;
typedef __attribute__((ext_vector_type(4))) float floatx4;

__device__ __forceinline__ float bf2f(u16 u) {
  unsigned int v = ((unsigned int)u) << 16;
  return __builtin_bit_cast(float, v);
}
__device__ __forceinline__ u16 f2bf(float f) {
  unsigned int u = __builtin_bit_cast(unsigned int, f);
  u += 0x7FFFu + ((u >> 16) & 1u);
  return (u16)(u >> 16);
}
__device__ __forceinline__ void gload_lds16(const void* g, void* l) {
  __builtin_amdgcn_global_load_lds(
      (const __attribute__((address_space(1))) unsigned int*)g,
      (__attribute__((address_space(3))) unsigned int*)l, 16, 0, 0);
}

// ---------- transpose+convert: in fp32 [K][N] -> out bf16 [N][K] ----------
__global__ __launch_bounds__(256) void transpose_f32_bf16(const float* __restrict__ in,
                                                          u16* __restrict__ out,
                                                          int K, int N) {
  __shared__ float tile[32][33];
  int n0 = blockIdx.x * 32, k0 = blockIdx.y * 32;
  int tx = threadIdx.x & 31, ty = threadIdx.x >> 5;  // ty 0..7
#pragma unroll
  for (int i = 0; i < 4; i++) {
    int r = ty + i * 8;
    tile[r][tx] = in[(size_t)(k0 + r) * N + n0 + tx];
  }
  __syncthreads();
#pragma unroll
  for (int i = 0; i < 4; i++) {
    int r = ty + i * 8;
    out[(size_t)(n0 + r) * K + k0 + tx] = f2bf(tile[tx][r]);
  }
}

// ---------------- layernorm (Bessel std, eps added to std) -> bf16 ----------------
__global__ __launch_bounds__(256) void ln_f32(const float* __restrict__ xin,
                                              const float* __restrict__ wgt,
                                              const float* __restrict__ bia,
                                              u16* __restrict__ out) {
  int row = blockIdx.x, t = threadIdx.x;
  const float* xr = xin + (size_t)row * 1024 + t * 4;
  float4 f = *(const float4*)xr;
  float v[4] = {f.x, f.y, f.z, f.w};
  float s1 = v[0] + v[1] + v[2] + v[3];
  float s2 = v[0] * v[0] + v[1] * v[1] + v[2] * v[2] + v[3] * v[3];
#pragma unroll
  for (int off = 32; off; off >>= 1) {
    s1 += __shfl_down(s1, off);
    s2 += __shfl_down(s2, off);
  }
  __shared__ float red[8];
  int lane = t & 63, w = t >> 6;
  if (lane == 0) { red[w] = s1; red[4 + w] = s2; }
  __syncthreads();
  s1 = red[0] + red[1] + red[2] + red[3];
  s2 = red[4] + red[5] + red[6] + red[7];
  float mean = s1 * (1.f / 1024.f);
  float var = (s2 - 1024.f * mean * mean) * (1.f / 1023.f);
  var = var < 0.f ? 0.f : var;
  float inv = 1.f / (sqrtf(var) + 1e-5f);
  float4 wv = *(const float4*)(wgt + t * 4);
  float4 bv = *(const float4*)(bia + t * 4);
  float wa[4] = {wv.x, wv.y, wv.z, wv.w};
  float ba[4] = {bv.x, bv.y, bv.z, bv.w};
#pragma unroll
  for (int j = 0; j < 4; j++)
    out[(size_t)row * 1024 + t * 4 + j] = f2bf(wa[j] * ((v[j] - mean) * inv) + ba[j]);
}

// ------- m97-style MFMA GEMM: C = A(bf16,[M][K]) @ Bt(bf16,[N][K])^T -------
template <int EPI>
__global__ __launch_bounds__(256) void gemm_bt(const u16* __restrict__ A,
                                               const u16* __restrict__ Bt,
                                               const float* __restrict__ bias,
                                               const float* __restrict__ res,
                                               void* __restrict__ outp,
                                               int ldc, int K) {
  __shared__ __align__(16) u16 As[128 * 64];
  __shared__ __align__(16) u16 Bs[128 * 64];
  int tid = threadIdx.x;
  int lane = tid & 63, w = tid >> 6;
  int quad = lane >> 4, c16 = lane & 15;
  int wm = w >> 1, wn = w & 1;
  int bn = blockIdx.x, bm = blockIdx.y;
  const u16* Ab = A + (size_t)bm * 128 * K;
  const u16* Bb = Bt + (size_t)bn * 128 * K;

  floatx4 zf = {0.f, 0.f, 0.f, 0.f};
  floatx4 acc[4][4];
#pragma unroll
  for (int i = 0; i < 4; i++)
#pragma unroll
    for (int j = 0; j < 4; j++) acc[i][j] = zf;

  int kIters = K >> 6;
  for (int kt = 0; kt < kIters; ++kt) {
    __syncthreads();
    const u16* Abase = Ab + kt * 64;
    const u16* Bbase = Bb + kt * 64;
#pragma unroll
    for (int t2 = 0; t2 < 4; ++t2) {
      int chunk = w * 4 + t2;
      int idx = chunk * 512 + lane * 8;
      int r = idx >> 6, cc = idx & 63;
      gload_lds16(Abase + (size_t)r * K + cc, &As[chunk * 512]);
      gload_lds16(Bbase + (size_t)r * K + cc, &Bs[chunk * 512]);
    }
    __syncthreads();
#pragma unroll
    for (int ks = 0; ks < 2; ++ks) {
      short8 af[4], bfr[4];
#pragma unroll
      for (int mt = 0; mt < 4; mt++)
        af[mt] = *(const short8*)&As[(wm * 64 + mt * 16 + c16) * 64 + ks * 32 + quad * 8];
#pragma unroll
      for (int nt = 0; nt < 4; nt++)
        bfr[nt] = *(const short8*)&Bs[(wn * 64 + nt * 16 + c16) * 64 + ks * 32 + quad * 8];
#pragma unroll
      for (int mt = 0; mt < 4; mt++)
#pragma unroll
        for (int nt = 0; nt < 4; nt++)
          acc[mt][nt] = __builtin_amdgcn_mfma_f32_16x16x32_bf16(af[mt], bfr[nt], acc[mt][nt], 0, 0, 0);
    }
  }
  int gm0 = bm * 128 + wm * 64;
  int gn0 = bn * 128 + wn * 64;
#pragma unroll
  for (int nt = 0; nt < 4; nt++) {
    int gn = gn0 + nt * 16 + c16;
    float bia = 0.f;
    if constexpr (EPI != 3) bia = bias[gn];
#pragma unroll
    for (int mt = 0; mt < 4; mt++) {
#pragma unroll
      for (int r = 0; r < 4; r++) {
        int gm = gm0 + mt * 16 + quad * 4 + r;
        size_t o = (size_t)gm * ldc + gn;
        float v = acc[mt][nt][r] + bia;
        if constexpr (EPI == 0) {
          ((u16*)outp)[o] = f2bf(v);
        } else if constexpr (EPI == 1) {
          ((float*)outp)[o] = v + res[o];
        } else if constexpr (EPI == 2) {
          float g = 0.5f * v * (1.f + tanhf(0.7978845608f * (v + 0.044715f * v * v * v)));
          ((u16*)outp)[o] = f2bf(g);
        } else {
          ((float*)outp)[o] += v;
        }
      }
    }
  }
}

// ---------------- flash attention v2: pair-tiled, 64-key tiles ----------------
// Ks stride 72 (pad); Vt [d][key ^ (d&56)] xor-swizzle; P stride 72.
__device__ __forceinline__ void attn_process(
    const short8& qf0, const short8& qf1,
    float* m_run, float* l_run, floatx4* oacc,
    const u16* __restrict__ Ks, const u16* __restrict__ Vt, u16* __restrict__ pw,
    int kt, int qt, int w, int quad, int c16, bool diag) {
  floatx4 zf = {0.f, 0.f, 0.f, 0.f};
  floatx4 s[4];
#pragma unroll
  for (int n = 0; n < 4; n++) {
    short8 kf0 = *(const short8*)&Ks[(n * 16 + c16) * 72 + quad * 8];
    short8 kf1 = *(const short8*)&Ks[(n * 16 + c16) * 72 + 32 + quad * 8];
    floatx4 a = zf;
    a = __builtin_amdgcn_mfma_f32_16x16x32_bf16(qf0, kf0, a, 0, 0, 0);
    a = __builtin_amdgcn_mfma_f32_16x16x32_bf16(qf1, kf1, a, 0, 0, 0);
    s[n] = a;
  }
  if (diag) {
#pragma unroll
    for (int n = 0; n < 4; n++) {
      int kg = kt * 64 + n * 16 + c16;
#pragma unroll
      for (int r = 0; r < 4; r++) {
        int qg = qt * 64 + w * 16 + quad * 4 + r;
        float sv = s[n][r] * 0.125f;
        s[n][r] = (kg > qg) ? -1e30f : sv;
      }
    }
  } else {
#pragma unroll
    for (int n = 0; n < 4; n++)
#pragma unroll
      for (int r = 0; r < 4; r++) s[n][r] *= 0.125f;
  }
  float mt[4];
#pragma unroll
  for (int r = 0; r < 4; r++)
    mt[r] = fmaxf(fmaxf(s[0][r], s[1][r]), fmaxf(s[2][r], s[3][r]));
#pragma unroll
  for (int off = 1; off < 16; off <<= 1)
#pragma unroll
    for (int r = 0; r < 4; r++) mt[r] = fmaxf(mt[r], __shfl_xor(mt[r], off));
  float alpha[4], lsum[4];
#pragma unroll
  for (int r = 0; r < 4; r++) {
    float mn = fmaxf(m_run[r], mt[r]);
    alpha[r] = __expf(m_run[r] - mn);
    m_run[r] = mn;
    lsum[r] = 0.f;
  }
#pragma unroll
  for (int n = 0; n < 4; n++)
#pragma unroll
    for (int r = 0; r < 4; r++) {
      float p = __expf(s[n][r] - m_run[r]);
      s[n][r] = p;
      lsum[r] += p;
    }
#pragma unroll
  for (int off = 1; off < 16; off <<= 1)
#pragma unroll
    for (int r = 0; r < 4; r++) lsum[r] += __shfl_xor(lsum[r], off);
#pragma unroll
  for (int r = 0; r < 4; r++) l_run[r] = l_run[r] * alpha[r] + lsum[r];
#pragma unroll
  for (int c = 0; c < 4; c++)
#pragma unroll
    for (int r = 0; r < 4; r++) oacc[c][r] *= alpha[r];
  // P (C-layout) -> per-wave LDS, stride 72
#pragma unroll
  for (int n = 0; n < 4; n++)
#pragma unroll
    for (int r = 0; r < 4; r++)
      pw[(quad * 4 + r) * 72 + n * 16 + c16] = f2bf(s[n][r]);
  short8 pf0 = *(const short8*)&pw[c16 * 72 + quad * 8];
  short8 pf1 = *(const short8*)&pw[c16 * 72 + 32 + quad * 8];
#pragma unroll
  for (int c = 0; c < 4; c++) {
    int d = c * 16 + c16;
    short8 vf0 = *(const short8*)&Vt[d * 64 + ((quad * 8) ^ (d & 56))];
    short8 vf1 = *(const short8*)&Vt[d * 64 + ((32 + quad * 8) ^ (d & 56))];
    oacc[c] = __builtin_amdgcn_mfma_f32_16x16x32_bf16(pf0, vf0, oacc[c], 0, 0, 0);
    oacc[c] = __builtin_amdgcn_mfma_f32_16x16x32_bf16(pf1, vf1, oacc[c], 0, 0, 0);
  }
}

// grid (16 pairs, 16 heads), 256 thr; block processes q-tiles pr and 31-pr in one kv sweep
__global__ __launch_bounds__(256) void attn_mfma2(const u16* __restrict__ qkvb,
                                                  u16* __restrict__ aout) {
  int pr = blockIdx.x, h = blockIdx.y;
  int qt0 = pr, qt1 = 31 - pr;
  int tid = threadIdx.x, lane = tid & 63, w = tid >> 6;
  int quad = lane >> 4, c16 = lane & 15;
  __shared__ __align__(16) u16 Ks[64 * 72];
  __shared__ __align__(16) u16 Vt[64 * 64];
  __shared__ __align__(16) u16 Ps[4][16 * 72];

  size_t qoffA = (size_t)(qt0 * 64 + w * 16 + c16) * 3072 + h * 64;
  short8 qfA0 = *(const short8*)(qkvb + qoffA + quad * 8);
  short8 qfA1 = *(const short8*)(qkvb + qoffA + 32 + quad * 8);
  size_t qoffB = (size_t)(qt1 * 64 + w * 16 + c16) * 3072 + h * 64;
  short8 qfB0 = *(const short8*)(qkvb + qoffB + quad * 8);
  short8 qfB1 = *(const short8*)(qkvb + qoffB + 32 + quad * 8);

  floatx4 zf = {0.f, 0.f, 0.f, 0.f};
  float mA[4], lA[4], mB[4], lB[4];
  floatx4 oA[4], oB[4];
#pragma unroll
  for (int r = 0; r < 4; r++) { mA[r] = -1e30f; lA[r] = 0.f; mB[r] = -1e30f; lB[r] = 0.f; }
#pragma unroll
  for (int c = 0; c < 4; c++) { oA[c] = zf; oB[c] = zf; }

  u16* pw = &Ps[w][0];
  for (int kt = 0; kt <= qt1; ++kt) {
    __syncthreads();
    // stage K (b128, stride 72) and V (xor-swizzled transpose) for 64 keys
#pragma unroll
    for (int u = 0; u < 2; u++) {
      int i = tid * 2 + u;             // 0..511
      int row = i >> 3, d8 = (i & 7) * 8;
      size_t gbase = (size_t)(kt * 64 + row) * 3072 + h * 64 + d8;
      short8 kv = *(const short8*)(qkvb + gbase + 1024);
      *(short8*)&Ks[row * 72 + d8] = kv;
      short8 vv = *(const short8*)(qkvb + gbase + 2048);
#pragma unroll
      for (int j = 0; j < 8; j++) {
        int d = d8 + j;
        Vt[d * 64 + (row ^ (d & 56))] = (u16)vv[j];
      }
    }
    __syncthreads();

    attn_process(qfB0, qfB1, mB, lB, oB, Ks, Vt, pw, kt, qt1, w, quad, c16, kt == qt1);
    if (kt <= qt0)
      attn_process(qfA0, qfA1, mA, lA, oA, Ks, Vt, pw, kt, qt0, w, quad, c16, kt == qt0);
  }

  size_t obA = (size_t)(qt0 * 64 + w * 16) * 1024 + h * 64;
  size_t obB = (size_t)(qt1 * 64 + w * 16) * 1024 + h * 64;
#pragma unroll
  for (int r = 0; r < 4; r++) {
    float invA = 1.f / lA[r], invB = 1.f / lB[r];
#pragma unroll
    for (int c = 0; c < 4; c++) {
      aout[obA + (size_t)(quad * 4 + r) * 1024 + c * 16 + c16] = f2bf(oA[c][r] * invA);
      aout[obB + (size_t)(quad * 4 + r) * 1024 + c * 16 + c16] = f2bf(oB[c][r] * invB);
    }
  }
}

extern "C" void kernel_launch(void* const* d_in, const int* in_sizes, int n_in,
                              void* d_out, int out_size, void* d_ws, size_t ws_size,
                              hipStream_t stream) {
  const float* x        = (const float*)d_in[0];
  const float* ln1_w    = (const float*)d_in[1];
  const float* ln1_b    = (const float*)d_in[2];
  const float* c_attn_w = (const float*)d_in[3];
  const float* c_attn_b = (const float*)d_in[4];
  const float* c_proj_w = (const float*)d_in[5];
  const float* c_proj_b = (const float*)d_in[6];
  const float* ln2_w    = (const float*)d_in[7];
  const float* ln2_b    = (const float*)d_in[8];
  const float* fc_w     = (const float*)d_in[9];
  const float* fc_b     = (const float*)d_in[10];
  const float* proj_w   = (const float*)d_in[11];
  const float* proj_b   = (const float*)d_in[12];

  char* ws = (char*)d_ws;
  // ---- phase 1 layout (peak = 28 MiB) ----
  u16* wt_attn   = (u16*)(ws + 0);          // [3072][1024] bf16, 6 MiB
  u16* wt_cproj  = (u16*)(ws + 6291456);    // [1024][1024] bf16, 2 MiB
  u16* ln1b      = (u16*)(ws + 8388608);    // [2048][1024] bf16 per batch, 4 MiB
  u16* qkvb      = (u16*)(ws + 12582912);   // [2048][3072] bf16 per batch, 12 MiB
  u16* attn_outb = (u16*)(ws + 25165824);   // [2048][1024] bf16 per batch, 4 MiB
  // ---- phase 2 layout (reuses everything) ----
  u16* wt_fc     = (u16*)(ws + 0);          // [4096][1024] bf16, 8 MiB
  u16* ln2b      = (u16*)(ws + 8388608);    // [4096][1024] bf16, 8 MiB
  u16* h_c       = (u16*)(ws + 16777216);   // [4096][1024] bf16 per chunk, 8 MiB
  u16* projT_c   = (u16*)(ws + 25165824);   // [1024][1024] bf16 per chunk, 2 MiB
  float* x1      = (float*)d_out;           // [4096][1024] fp32; final out in place

  transpose_f32_bf16<<<dim3(96, 32), 256, 0, stream>>>(c_attn_w, wt_attn, 1024, 3072);
  transpose_f32_bf16<<<dim3(32, 32), 256, 0, stream>>>(c_proj_w, wt_cproj, 1024, 1024);

  for (int b = 0; b < 2; b++) {
    size_t boff = (size_t)b * 2048 * 1024;
    ln_f32<<<2048, 256, 0, stream>>>(x + boff, ln1_w, ln1_b, ln1b);
    gemm_bt<0><<<dim3(24, 16), 256, 0, stream>>>(ln1b, wt_attn, c_attn_b, nullptr,
                                                 qkvb, 3072, 1024);
    attn_mfma2<<<dim3(16, 16), 256, 0, stream>>>(qkvb, attn_outb);
    gemm_bt<1><<<dim3(8, 16), 256, 0, stream>>>(attn_outb, wt_cproj, c_proj_b,
                                                x + boff, x1 + boff, 1024, 1024);
  }

  transpose_f32_bf16<<<dim3(128, 32), 256, 0, stream>>>(fc_w, wt_fc, 1024, 4096);
  ln_f32<<<4096, 256, 0, stream>>>(x1, ln2_w, ln2_b, ln2b);
  for (int c = 0; c < 4; c++) {
    transpose_f32_bf16<<<dim3(32, 32), 256, 0, stream>>>(proj_w + (size_t)c * 1024 * 1024,
                                                         projT_c, 1024, 1024);
    gemm_bt<2><<<dim3(8, 32), 256, 0, stream>>>(ln2b, wt_fc + (size_t)c * 1024 * 1024,
                                                fc_b + c * 1024, nullptr, h_c, 1024, 1024);
    if (c < 3)
      gemm_bt<3><<<dim3(8, 32), 256, 0, stream>>>(h_c, projT_c, nullptr, nullptr,
                                                  x1, 1024, 1024);
    else
      gemm_bt<4><<<dim3(8, 32), 256, 0, stream>>>(h_c, projT_c, proj_b, nullptr,
                                                  x1, 1024, 1024);
  }
}